// Round 3
// baseline (890.910 us; speedup 1.0000x reference)
//
#include <hip/hip_runtime.h>
#include <hip/hip_bf16.h>
#include <math.h>

// Problem constants
#define B_ROWS 8192
#define D_IN 1024
#define D_OUT 1024
#define NEXP 16
#define NCOL 256     // 15*8 z-cols (0..119), 16*8 a-cols (120..247), pad 256
#define KC 16        // k-chunk
#define RTILE 16     // rows per block

typedef float f32x4 __attribute__((ext_vector_type(4)));

// ---------------- K0: pack/transpose weights into Wt[d][col] ----------------
__global__ void wt_pack_kernel(const float* __restrict__ Wz,
                               const float* __restrict__ Ww,
                               float* __restrict__ Wt) {
    int d = blockIdx.x;        // 0..1023
    int col = threadIdx.x;     // 0..255
    float v = 0.0f;
    if (col < 120) {
        int n = col >> 3, k = col & 7;
        v = Wz[n * (D_IN * 8) + d * 8 + k];
    } else if (col < 248) {
        int c = col - 120;
        int n = c >> 3, k = c & 7;
        v = Ww[n * (D_IN * 8) + d * 8 + k];
    }
    Wt[d * NCOL + col] = v;
}

// ---------------- fused: GEMM(16x256) + gate + weighted f-sum ---------------
__global__ __launch_bounds__(256) void fused_kernel(
    const float* __restrict__ x,     // (8192,1024)
    const float* __restrict__ Wt,    // (1024,256) packed
    const float* __restrict__ bz,    // (15,8)
    const float* __restrict__ bw,    // (16,8)
    const float* __restrict__ perm,  // (8,16,16)
    const float* __restrict__ f,     // (8192,1024,16)
    float* __restrict__ y)           // (8192,1024)
{
    __shared__ float wsh[KC * NCOL];     // 16 KB: W chunk; reused as ZA tile
    __shared__ float xs[KC][RTILE];      // 1 KB: x chunk (transposed)
    __shared__ float perm_s[2048];       // 8 KB
    __shared__ float bz_s[120];
    __shared__ float bw_s[128];
    __shared__ float wexp_s[RTILE * 16]; // 1 KB: final expert weights

    const int tid = threadIdx.x;
    const int row0 = blockIdx.x * RTILE;

    // ---- stage small constants ----
    {
        const float4* p4 = (const float4*)perm;
        float4* s4 = (float4*)perm_s;
        s4[tid] = p4[tid];
        s4[256 + tid] = p4[256 + tid];
        if (tid < 120) bz_s[tid] = bz[tid];
        if (tid < 128) bw_s[tid] = bw[tid];
    }

    // ---- phase A: GEMM  ZA[16][256] = x[row0..+16][:] @ Wt ----
    const int rg = tid >> 6;             // 0..3  -> rows rg*4..+3
    const int cg = tid & 63;             // 0..63 -> cols cg*4..+3
    const int sxRow = tid >> 2;          // for tid<64: x-stage row 0..15
    const int sxK = (tid & 3) << 2;      // x-stage k offset 0,4,8,12

    float acc[4][4];
#pragma unroll
    for (int i = 0; i < 4; ++i)
#pragma unroll
        for (int j = 0; j < 4; ++j) acc[i][j] = 0.0f;

    // prefetch chunk 0
    float4 px, pw[4];
    if (tid < 64) px = *(const float4*)&x[(row0 + sxRow) * D_IN + sxK];
#pragma unroll
    for (int j = 0; j < 4; ++j) {
        const int flat = j * 256 + tid;
        const int k = flat >> 6;
        const int c4 = (flat & 63) << 2;
        pw[j] = *(const float4*)&Wt[k * NCOL + c4];
    }

    for (int kc = 0; kc < D_IN; kc += KC) {
        // commit prefetched chunk to LDS
        if (tid < 64) {
            xs[sxK + 0][sxRow] = px.x;
            xs[sxK + 1][sxRow] = px.y;
            xs[sxK + 2][sxRow] = px.z;
            xs[sxK + 3][sxRow] = px.w;
        }
#pragma unroll
        for (int j = 0; j < 4; ++j) {
            const int flat = j * 256 + tid;
            const int k = flat >> 6;
            const int c4 = (flat & 63) << 2;
            *(float4*)&wsh[k * NCOL + c4] = pw[j];
        }
        __syncthreads();
        // prefetch next chunk
        if (kc + KC < D_IN) {
            if (tid < 64) px = *(const float4*)&x[(row0 + sxRow) * D_IN + kc + KC + sxK];
#pragma unroll
            for (int j = 0; j < 4; ++j) {
                const int flat = j * 256 + tid;
                const int k = flat >> 6;
                const int c4 = (flat & 63) << 2;
                pw[j] = *(const float4*)&Wt[(kc + KC + k) * NCOL + c4];
            }
        }
#pragma unroll
        for (int kk = 0; kk < KC; ++kk) {
            const float4 xa = *(const float4*)&xs[kk][rg << 2];
            const float4 wv = *(const float4*)&wsh[kk * NCOL + (cg << 2)];
            const float xr[4] = {xa.x, xa.y, xa.z, xa.w};
            const float wc[4] = {wv.x, wv.y, wv.z, wv.w};
#pragma unroll
            for (int i = 0; i < 4; ++i)
#pragma unroll
                for (int j = 0; j < 4; ++j) acc[i][j] = fmaf(xr[i], wc[j], acc[i][j]);
        }
        __syncthreads();
    }

    // epilogue: ZA tile -> LDS (reuse wsh)
#pragma unroll
    for (int i = 0; i < 4; ++i) {
        float4 o;
        o.x = acc[i][0]; o.y = acc[i][1]; o.z = acc[i][2]; o.w = acc[i][3];
        *(float4*)&wsh[((rg << 2) + i) * NCOL + (cg << 2)] = o;
    }
    __syncthreads();

    // ---- phase B: gate (in-wave, 16 lanes per row) ----
    {
        const int gr = tid >> 4;   // row 0..15
        const int gn = tid & 15;   // expert/leaf 0..15
        const float* za = &wsh[gr * NCOL];

        float prob[8];
#pragma unroll
        for (int kk = 0; kk < 8; ++kk) prob[kk] = 1.0f;
#pragma unroll
        for (int L = 0; L < 4; ++L) {
            const int node = (1 << L) - 1 + (gn >> (4 - L));
            const int bit = (gn >> (3 - L)) & 1;
#pragma unroll
            for (int kk = 0; kk < 8; ++kk) {
                const float v = za[node * 8 + kk] + bz_s[node * 8 + kk];
                float p;
                if (v <= -0.5f) p = 0.0f;
                else if (v >= 0.5f) p = 1.0f;
                else p = fmaf(-2.0f * v * v, v, fmaf(1.5f, v, 0.5f));
                prob[kk] *= bit ? (1.0f - p) : p;
            }
        }
        float logit[8];
        float m = -3.4e38f;
#pragma unroll
        for (int kk = 0; kk < 8; ++kk) {
            const float a = za[120 + gn * 8 + kk] + bw_s[gn * 8 + kk];
            logit[kk] = (prob[kk] <= 0.0f) ? -3.4e38f : (a + logf(prob[kk] + 1e-8f));
            m = fmaxf(m, logit[kk]);
        }
        // row max across the 16 lanes of this row
#pragma unroll
        for (int s = 1; s < 16; s <<= 1) m = fmaxf(m, __shfl_xor(m, s, 16));

        float u[8];
#pragma unroll
        for (int kk = 0; kk < 8; ++kk) u[kk] = expf(logit[kk] - m);

        // partial[l] = sum_kk u[kk] * perm[kk][gn][l]
        float part[16];
#pragma unroll
        for (int l = 0; l < 16; ++l) {
            float s2 = 0.0f;
#pragma unroll
            for (int kk = 0; kk < 8; ++kk)
                s2 = fmaf(u[kk], perm_s[kk * 256 + gn * 16 + l], s2);
            part[l] = s2;
        }
        // sum across the 16 lanes (each lane ends with full G[0..15])
#pragma unroll
        for (int s = 1; s < 16; s <<= 1) {
#pragma unroll
            for (int l = 0; l < 16; ++l) part[l] += __shfl_xor(part[l], s, 16);
        }
        float tot = 0.0f;
#pragma unroll
        for (int l = 0; l < 16; ++l) tot += part[l];
        wexp_s[gr * 16 + gn] = part[gn] / tot;
    }
    __syncthreads();

    // ---- phase C: y[r][d] = sum_n f[r][d][n] * w[r][n] ----
    for (int r = 0; r < RTILE; ++r) {
        const float4 w0 = *(const float4*)&wexp_s[r * 16 + 0];
        const float4 w1 = *(const float4*)&wexp_s[r * 16 + 4];
        const float4 w2 = *(const float4*)&wexp_s[r * 16 + 8];
        const float4 w3 = *(const float4*)&wexp_s[r * 16 + 12];
        const long grow = (long)(row0 + r);
        const float* fbase = f + grow * D_OUT * NEXP;
        float* ybase = y + grow * D_OUT;
#pragma unroll
        for (int c = 0; c < 4; ++c) {
            const int d = c * 256 + tid;
            const f32x4* f4 = (const f32x4*)(fbase + (long)d * NEXP);
            const f32x4 a0 = __builtin_nontemporal_load(f4 + 0);
            const f32x4 a1 = __builtin_nontemporal_load(f4 + 1);
            const f32x4 a2 = __builtin_nontemporal_load(f4 + 2);
            const f32x4 a3 = __builtin_nontemporal_load(f4 + 3);
            float rsum = a0.x * w0.x + a0.y * w0.y + a0.z * w0.z + a0.w * w0.w
                       + a1.x * w1.x + a1.y * w1.y + a1.z * w1.z + a1.w * w1.w
                       + a2.x * w2.x + a2.y * w2.y + a2.z * w2.z + a2.w * w2.w
                       + a3.x * w3.x + a3.y * w3.y + a3.z * w3.z + a3.w * w3.w;
            __builtin_nontemporal_store(rsum, ybase + d);
        }
    }
}

// ---------------- launch ----------------------------------------------------
extern "C" void kernel_launch(void* const* d_in, const int* in_sizes, int n_in,
                              void* d_out, int out_size, void* d_ws, size_t ws_size,
                              hipStream_t stream) {
    const float* f = (const float*)d_in[0];     // (8192, 1024, 16)
    const float* x = (const float*)d_in[1];     // (8192, 1024)
    const float* perm = (const float*)d_in[2];  // (8, 16, 16)
    const float* Wz = (const float*)d_in[3];    // (15, 1024, 8)
    const float* bz = (const float*)d_in[4];    // (15, 8)
    const float* Ww = (const float*)d_in[5];    // (16, 1024, 8)
    const float* bw = (const float*)d_in[6];    // (16, 8)
    float* y = (float*)d_out;                   // (8192, 1024)

    float* Wt = (float*)d_ws;                   // 1024*256 floats = 1 MB

    wt_pack_kernel<<<dim3(D_IN), dim3(NCOL), 0, stream>>>(Wz, Ww, Wt);
    fused_kernel<<<dim3(B_ROWS / RTILE), dim3(256), 0, stream>>>(
        x, Wt, bz, bw, perm, f, y);
}